// Round 1
// baseline (425.161 us; speedup 1.0000x reference)
//
#include <hip/hip_runtime.h>
#include <cmath>

constexpr int kB = 8;
constexpr int kN = 1024;
constexpr int kH = 768;
constexpr float kNeg = 1000000000000.0f;  // same fp32 rounding as reference

// ---------------------------------------------------------------------------
// Kernel 1: outputs = lhs @ w1 + b1 (8192x768 @ 768x128), RoPE -> qw, kw
//           bias    = (lhs @ w2 + b2) / 2, stored transposed biasT[b][e'][n]
// 16 rows per block, 256 threads: thread = (colgroup c 0..31, rowpair r2 0..7)
// cols 4c..4c+3 => q dims (2c,2c+1) from cols 4c,4c+2; k dims from 4c+1,4c+3.
// ---------------------------------------------------------------------------
__global__ __launch_bounds__(256) void k1_proj_rope(
    const float* __restrict__ lhs, const float* __restrict__ w1,
    const float* __restrict__ b1, const float* __restrict__ w2,
    const float* __restrict__ b2, float* __restrict__ qw,
    float* __restrict__ kw, float* __restrict__ biasT)
{
  __shared__ float xs[16][kH];  // 48 KB
  const int t = threadIdx.x;
  const int g0 = blockIdx.x * 16;

  // stage 16 rows of lhs (3072 float4, 12 per thread, coalesced)
  const float4* lhs4 = reinterpret_cast<const float4*>(lhs + (size_t)g0 * kH);
  float4* xs4 = reinterpret_cast<float4*>(&xs[0][0]);
#pragma unroll
  for (int p = 0; p < 12; ++p) xs4[t + p * 256] = lhs4[t + p * 256];
  __syncthreads();

  const int c = t & 31;
  const int r2 = t >> 5;
  float acc0[4] = {0.f, 0.f, 0.f, 0.f};
  float acc1[4] = {0.f, 0.f, 0.f, 0.f};
  const float* xr0 = xs[r2];
  const float* xr1 = xs[r2 + 8];
  for (int h = 0; h < kH; h += 4) {
    float x0[4], x1[4];
    *reinterpret_cast<float4*>(x0) = *reinterpret_cast<const float4*>(&xr0[h]);
    *reinterpret_cast<float4*>(x1) = *reinterpret_cast<const float4*>(&xr1[h]);
#pragma unroll
    for (int hh = 0; hh < 4; ++hh) {
      const float4 wv =
          *reinterpret_cast<const float4*>(&w1[(size_t)(h + hh) * 128 + 4 * c]);
      acc0[0] += x0[hh] * wv.x; acc0[1] += x0[hh] * wv.y;
      acc0[2] += x0[hh] * wv.z; acc0[3] += x0[hh] * wv.w;
      acc1[0] += x1[hh] * wv.x; acc1[1] += x1[hh] * wv.y;
      acc1[2] += x1[hh] * wv.z; acc1[3] += x1[hh] * wv.w;
    }
  }
  float bb[4];
  *reinterpret_cast<float4*>(bb) = *reinterpret_cast<const float4*>(&b1[4 * c]);

  // inv_freq = 10000^(-c/32) = exp2(-c * log2(10000)/32)
  const float inv = exp2f(-(float)c * 0.41524101186092f);
#pragma unroll
  for (int rr = 0; rr < 2; ++rr) {
    const float* acc = rr ? acc1 : acc0;
    const int g = g0 + r2 + rr * 8;
    const int n = g & (kN - 1);
    float si, co;
    sincosf((float)n * inv, &si, &co);
    const float oq0 = acc[0] + bb[0], ok0 = acc[1] + bb[1];
    const float oq1 = acc[2] + bb[2], ok1 = acc[3] + bb[3];
    float2 qv = make_float2(oq0 * co - oq1 * si, oq1 * co + oq0 * si);
    float2 kv = make_float2(ok0 * co - ok1 * si, ok1 * co + ok0 * si);
    *reinterpret_cast<float2*>(&qw[(size_t)g * 64 + 2 * c]) = qv;
    *reinterpret_cast<float2*>(&kw[(size_t)g * 64 + 2 * c]) = kv;
  }

  // bias: 16 rows x 18 cols = 288 dots (xs unchanged, no barrier needed)
  for (int idx = t; idx < 288; idx += 256) {
    const int row = idx / 18, col = idx % 18;
    float s = 0.f;
    for (int h = 0; h < kH; h += 4) {
      const float4 xv = *reinterpret_cast<const float4*>(&xs[row][h]);
      s += xv.x * w2[(size_t)h * 18 + col];
      s += xv.y * w2[(size_t)(h + 1) * 18 + col];
      s += xv.z * w2[(size_t)(h + 2) * 18 + col];
      s += xv.w * w2[(size_t)(h + 3) * 18 + col];
    }
    const int g = g0 + row;
    const int b = g >> 10, n = g & (kN - 1);
    biasT[((size_t)b * 18 + col) * kN + n] = (s + b2[col]) * 0.5f;
  }
}

// ---------------------------------------------------------------------------
// Kernel 2: out[b,e,m,n] = dot(qw[b,m],kw[b,n])/8 + bE[b,e,n] + bO[b,e,m]
//           + mask + causal tril.  64x64 tile/block, 4m x 4n per thread,
//           n set = {tx + 16j}: ds_read_b128 hits 8 banks 2-way (free).
// ---------------------------------------------------------------------------
__global__ __launch_bounds__(256) void k2_logits(
    const float* __restrict__ qw, const float* __restrict__ kw,
    const float* __restrict__ biasT, const float* __restrict__ mask,
    float* __restrict__ out)
{
  constexpr int LD = 68;  // 16B-aligned rows, stride mod 32 = 4
  __shared__ float qs[64 * LD];
  __shared__ float ks[64 * LD];
  __shared__ float bE[9 * 64];
  __shared__ float bO[9 * 64];
  __shared__ float mrow_s[64];
  __shared__ float mcol_s[64];

  const int t = threadIdx.x;
  const int b = blockIdx.z;
  const int m0 = blockIdx.y * 64;
  const int n0 = blockIdx.x * 64;

  const float* qg = qw + ((size_t)b * kN + m0) * 64;
  const float* kg = kw + ((size_t)b * kN + n0) * 64;
#pragma unroll
  for (int p = 0; p < 4; ++p) {
    const int idx = t + p * 256;      // 0..1023
    const int row = idx >> 4;
    const int c4 = (idx & 15) << 2;
    *reinterpret_cast<float4*>(&qs[row * LD + c4]) =
        *reinterpret_cast<const float4*>(&qg[row * 64 + c4]);
    *reinterpret_cast<float4*>(&ks[row * LD + c4]) =
        *reinterpret_cast<const float4*>(&kg[row * 64 + c4]);
  }
  for (int idx = t; idx < 576; idx += 256) {
    const int e = idx >> 6, x = idx & 63;
    bE[idx] = biasT[((size_t)b * 18 + 2 * (idx >> 6)) * kN + n0 + x];
    bO[idx] = biasT[((size_t)b * 18 + 2 * e + 1) * kN + m0 + x];
  }
  if (t < 64) mrow_s[t] = mask[b * kN + m0 + t];
  else if (t < 128) mcol_s[t - 64] = mask[b * kN + n0 + (t - 64)];
  __syncthreads();

  const int tx = t & 15;
  const int ty = t >> 4;
  const int ml = ty << 2;  // 4 m rows: ml..ml+3

  float acc[4][4] = {};
  for (int d = 0; d < 64; d += 4) {
    float4 q[4], k[4];
#pragma unroll
    for (int i = 0; i < 4; ++i)
      q[i] = *reinterpret_cast<const float4*>(&qs[(ml + i) * LD + d]);
#pragma unroll
    for (int j = 0; j < 4; ++j)
      k[j] = *reinterpret_cast<const float4*>(&ks[(tx + 16 * j) * LD + d]);
#pragma unroll
    for (int i = 0; i < 4; ++i)
#pragma unroll
      for (int j = 0; j < 4; ++j)
        acc[i][j] += q[i].x * k[j].x + q[i].y * k[j].y +
                     q[i].z * k[j].z + q[i].w * k[j].w;
  }

  float mr[4], mc[4];
#pragma unroll
  for (int i = 0; i < 4; ++i) mr[i] = mrow_s[ml + i];
#pragma unroll
  for (int j = 0; j < 4; ++j) mc[j] = mcol_s[tx + 16 * j];

  const size_t obase = (size_t)b * 9 * kN * kN;
  for (int e = 0; e < 9; ++e) {
    float be[4], bo[4];
#pragma unroll
    for (int j = 0; j < 4; ++j) be[j] = bE[e * 64 + tx + 16 * j];
#pragma unroll
    for (int i = 0; i < 4; ++i) bo[i] = bO[e * 64 + ml + i];
#pragma unroll
    for (int i = 0; i < 4; ++i) {
      const int m = m0 + ml + i;
      float* orow = out + obase + ((size_t)e * kN + m) * kN;
#pragma unroll
      for (int j = 0; j < 4; ++j) {
        const int n = n0 + tx + 16 * j;
        float v = acc[i][j] * 0.125f + be[j] + bo[i];
        v = v * mr[i] - kNeg * (1.f - mr[i]);   // row mask (exact for mask=1)
        v = v * mc[j] - kNeg * (1.f - mc[j]);   // col mask
        if (m > n) v -= kNeg;                    // tril(k=-1)
        orow[n] = v;
      }
    }
  }
}

extern "C" void kernel_launch(void* const* d_in, const int* in_sizes, int n_in,
                              void* d_out, int out_size, void* d_ws, size_t ws_size,
                              hipStream_t stream) {
  const float* lhs  = (const float*)d_in[0];
  const float* mask = (const float*)d_in[1];
  const float* w1   = (const float*)d_in[2];
  const float* b1   = (const float*)d_in[3];
  const float* w2   = (const float*)d_in[4];
  const float* b2   = (const float*)d_in[5];
  float* out = (float*)d_out;

  float* qw    = (float*)d_ws;                       // 8192*64 fp32 = 2 MB
  float* kwp   = qw  + (size_t)kB * kN * 64;         // 2 MB
  float* biasT = kwp + (size_t)kB * kN * 64;         // 8*18*1024 = 576 KB

  k1_proj_rope<<<dim3(kB * kN / 16), 256, 0, stream>>>(lhs, w1, b1, w2, b2,
                                                       qw, kwp, biasT);
  k2_logits<<<dim3(kN / 64, kN / 64, kB), 256, 0, stream>>>(qw, kwp, biasT,
                                                            mask, out);
}